// Round 6
// baseline (475.249 us; speedup 1.0000x reference)
//
#include <hip/hip_runtime.h>
#include <math.h>

// Problem constants
// B=64, N=384, NFEAT=16, E=3, NHID=NOUT=128, ST_HID=64, ST_OUT=16
#define ROWS 24576            // B*N
#define ADJ_BE (384*384)      // per (b,e) adj matrix elems

typedef _Float16 h4v __attribute__((ext_vector_type(4)));
typedef _Float16 h8v __attribute__((ext_vector_type(8)));
typedef float f32x4 __attribute__((ext_vector_type(4)));

#define SPLIT_SCALE 2048.0f
#define INV_SPLIT_SCALE (1.0f / 2048.0f)

// ---------------- kernel 0: M1[e] = emb^T @ W1[e]  (3 x 16 x 128, one block) ----------------
__global__ __launch_bounds__(256) void k_prep(const float* __restrict__ emb_w,
        const float* __restrict__ W1, float* __restrict__ M1) {
    __shared__ float embL[16][16];   // emb[f][d]
    int t = threadIdx.x;
    embL[t >> 4][t & 15] = emb_w[t];
    __syncthreads();
    int c = t & 127, half = t >> 7;  // cols, d-halves
#pragma unroll
    for (int e = 0; e < 3; ++e) {
        float w[16];
#pragma unroll
        for (int f = 0; f < 16; ++f) w[f] = W1[(size_t)(e * 16 + f) * 128 + c];
#pragma unroll
        for (int dd = 0; dd < 8; ++dd) {
            int d = half * 8 + dd;
            float acc = 0.f;
#pragma unroll
            for (int f = 0; f < 16; ++f) acc = fmaf(embL[f][d], w[f], acc);
            M1[(size_t)(e * 16 + d) * 128 + c] = acc;
        }
    }
}

// ---------------- kernel 1: S1[b,e] = x[b] @ M1[e]  (64x128 tile, K=16), split-store ----------------
__global__ __launch_bounds__(256) void k_support16(const float* __restrict__ x,
        const float* __restrict__ M1, _Float16* __restrict__ Sh, _Float16* __restrict__ Sl) {
    int rt = blockIdx.x, e = blockIdx.y;
    int b = rt / 6, n0 = (rt % 6) * 64;
    const float* Xp = x + (size_t)rt * 64 * 16;
    const float* Mp = M1 + (size_t)e * 16 * 128;
    __shared__ float xT[16][68];     // [f][node]
    __shared__ float mB[16][132];    // [f][col]
    int t = threadIdx.x;
    {   // x tile 64x16 = 256 f4, transposed
        int r = t >> 2, q = t & 3;
        float4 v = *(const float4*)(Xp + (size_t)r * 16 + q * 4);
        xT[q*4+0][r] = v.x; xT[q*4+1][r] = v.y; xT[q*4+2][r] = v.z; xT[q*4+3][r] = v.w;
    }
#pragma unroll
    for (int p = 0; p < 2; ++p) {    // M1 16x128 = 512 f4
        int idx = t + p * 256;
        int r = idx >> 5, q = idx & 31;
        *(float4*)&mB[r][q * 4] = *(const float4*)(Mp + (size_t)r * 128 + q * 4);
    }
    __syncthreads();
    int tx = t & 15, ty = t >> 4;
    float acc[4][8] = {};
#pragma unroll
    for (int k = 0; k < 16; ++k) {
        float4 av = *(const float4*)&xT[k][4 * ty];
        float4 b0 = *(const float4*)&mB[k][4 * tx];
        float4 b1 = *(const float4*)&mB[k][64 + 4 * tx];
        float a[4] = {av.x, av.y, av.z, av.w};
        float bb[8] = {b0.x, b0.y, b0.z, b0.w, b1.x, b1.y, b1.z, b1.w};
#pragma unroll
        for (int i = 0; i < 4; ++i)
#pragma unroll
            for (int j = 0; j < 8; ++j)
                acc[i][j] = fmaf(a[i], bb[j], acc[i][j]);
    }
    size_t base = (size_t)(b * 3 + e) * 128 * 384;
#pragma unroll
    for (int j = 0; j < 8; ++j) {
        int n = (j < 4) ? (4 * tx + j) : (64 + 4 * tx + j - 4);
        h4v hh, ll;
#pragma unroll
        for (int i = 0; i < 4; ++i) {
            float v = acc[i][j];
            _Float16 h = (_Float16)v;
            hh[i] = h;
            ll[i] = (_Float16)((v - (float)h) * SPLIT_SCALE);
        }
        size_t off = base + (size_t)n * 384 + n0 + 4 * ty;
        *(h4v*)(Sh + off) = hh;
        *(h4v*)(Sl + off) = ll;
    }
}

// ---------------- kernel 2: S_t hi/lo fp16 = (h[b] @ W[e])^T  (64x128 tile, K=128) ----------------
__global__ __launch_bounds__(256) void k_support(const float* __restrict__ hin,
        const float* __restrict__ W, _Float16* __restrict__ Sh, _Float16* __restrict__ Sl) {
    int rt = blockIdx.x, e = blockIdx.y;
    int b = rt / 6, n0 = (rt % 6) * 64;
    const float* Hp = hin + (size_t)rt * 64 * 128;
    const float* Wp = W + (size_t)e * 128 * 128;
    __shared__ float aT[32][68];    // [k][row]
    __shared__ float bT[32][132];   // [k][col]
    int t = threadIdx.x;
    int tx = t & 15;
    int ty = t >> 4;
    float acc[4][8] = {};
    for (int k0 = 0; k0 < 128; k0 += 32) {
        __syncthreads();
#pragma unroll
        for (int p = 0; p < 2; ++p) {          // h tile 64x32 transposed (512 f4)
            int idx = t + p * 256;
            int r = idx >> 3, q = idx & 7;
            float4 v = *(const float4*)(Hp + (size_t)r * 128 + k0 + q * 4);
            aT[q*4+0][r] = v.x; aT[q*4+1][r] = v.y; aT[q*4+2][r] = v.z; aT[q*4+3][r] = v.w;
        }
#pragma unroll
        for (int p = 0; p < 4; ++p) {          // W tile 32x128 (1024 f4)
            int idx = t + p * 256;
            int r = idx >> 5, q = idx & 31;
            *(float4*)&bT[r][q * 4] = *(const float4*)(Wp + (size_t)(k0 + r) * 128 + q * 4);
        }
        __syncthreads();
#pragma unroll
        for (int k = 0; k < 32; ++k) {
            float4 av = *(const float4*)&aT[k][4 * ty];
            float4 b0 = *(const float4*)&bT[k][4 * tx];
            float4 b1 = *(const float4*)&bT[k][64 + 4 * tx];
            float a[4] = {av.x, av.y, av.z, av.w};
            float bb[8] = {b0.x, b0.y, b0.z, b0.w, b1.x, b1.y, b1.z, b1.w};
#pragma unroll
            for (int i = 0; i < 4; ++i)
#pragma unroll
                for (int j = 0; j < 8; ++j)
                    acc[i][j] = fmaf(a[i], bb[j], acc[i][j]);
        }
    }
    size_t base = (size_t)(b * 3 + e) * 128 * 384;
#pragma unroll
    for (int j = 0; j < 8; ++j) {
        int n = (j < 4) ? (4 * tx + j) : (64 + 4 * tx + j - 4);
        h4v hh, ll;
#pragma unroll
        for (int i = 0; i < 4; ++i) {
            float v = acc[i][j];
            _Float16 h = (_Float16)v;
            hh[i] = h;
            ll[i] = (_Float16)((v - (float)h) * SPLIT_SCALE);
        }
        size_t off = base + (size_t)n * 384 + n0 + 4 * ty;
        *(h4v*)(Sh + off) = hh;
        *(h4v*)(Sl + off) = ll;
    }
}

// ---------------- kernel 3: out[b] += relu?(adj[b,e] @ S[b,e]) via 4-term split fp16 MFMA ----------------
// 96x128 block tile, grid (4 mt, 3 e, 64 b) = 768 blocks. 4 waves as 2x2 grid of 48x64 wave
// tiles (3x4 MFMA subtiles 16x16, K=32/chunk).
// A = ah + al/2^11 (al scaled), B = bh + bl/2^11 (bl scaled).
// acc0 += ah*bh;  acc1 += ah*bl + al*bh + (al*2^-11)*bl;  D = acc0 + acc1/2^11.  (all 4 terms)
template <int RELU>
__global__ __launch_bounds__(256, 3) void k_adj_mfma(const float* __restrict__ adj,
        const _Float16* __restrict__ Sh, const _Float16* __restrict__ Sl,
        float* __restrict__ out) {
    int mt = blockIdx.x, e = blockIdx.y, b = blockIdx.z;
    const float* A = adj + (size_t)(b * 3 + e) * ADJ_BE + (size_t)mt * 96 * 384;
    const _Float16* Bh = Sh + (size_t)(b * 3 + e) * 128 * 384;
    const _Float16* Bl = Sl + (size_t)(b * 3 + e) * 128 * 384;
    float* O = out + ((size_t)b * 384 + mt * 96) * 128;

    // fragment-linear LDS: [plane][subtile][quad(k8)][lane16] -> 8 f16 (16 B slots)
    __shared__ _Float16 Af[2][6][4][16][8];   // 12 KB  (96 rows x 32 k)
    __shared__ _Float16 Bf[2][8][4][16][8];   // 16 KB  (128 cols x 32 k)

    int t = threadIdx.x;
    int wave = t >> 6, lane = t & 63;
    int l16 = lane & 15, quad = lane >> 4;
    int wm = wave >> 1, wn = wave & 1;        // wave tile: rows 48*wm.., cols 64*wn..

    f32x4 acc0[3][4], acc1[3][4];
#pragma unroll
    for (int i = 0; i < 3; ++i)
#pragma unroll
        for (int j = 0; j < 4; ++j) {
            acc0[i][j] = f32x4{0.f, 0.f, 0.f, 0.f};
            acc1[i][j] = f32x4{0.f, 0.f, 0.f, 0.f};
        }

    for (int k0 = 0; k0 < 384; k0 += 32) {
        __syncthreads();
        // stage A: 96x32 fp32 -> hi + scaled-residual fp16 frags. 768 float4 chunks, 3/thread.
#pragma unroll
        for (int p = 0; p < 3; ++p) {
            int idx = t + p * 256;            // 0..767
            int r = idx >> 3, q4 = idx & 7;   // row, 4-float k-group
            float4 v = *(const float4*)(A + (size_t)r * 384 + k0 + 4 * q4);
            h4v hh, ll;
            float vv[4] = {v.x, v.y, v.z, v.w};
#pragma unroll
            for (int c = 0; c < 4; ++c) {
                _Float16 h = (_Float16)vv[c];
                hh[c] = h;
                ll[c] = (_Float16)((vv[c] - (float)h) * SPLIT_SCALE);
            }
            *(h4v*)&Af[0][r >> 4][q4 >> 1][r & 15][(q4 & 1) * 4] = hh;
            *(h4v*)&Af[1][r >> 4][q4 >> 1][r & 15][(q4 & 1) * 4] = ll;
        }
        // stage B: 128 cols x 32 k per plane, 16-B chunks, 2/thread/plane
#pragma unroll
        for (int p = 0; p < 2; ++p) {
            int idx = t + p * 256;            // 0..511
            int n = idx >> 2, q8 = idx & 3;
            size_t off = (size_t)n * 384 + k0 + 8 * q8;
            *(h8v*)&Bf[0][n >> 4][q8][n & 15][0] = *(const h8v*)(Bh + off);
            *(h8v*)&Bf[1][n >> 4][q8][n & 15][0] = *(const h8v*)(Bl + off);
        }
        __syncthreads();
        // A fragments (reused across j); a_d = al * 2^-11 for the ll term
        h8v a_h[3], a_l[3], a_d[3];
#pragma unroll
        for (int i = 0; i < 3; ++i) {
            a_h[i] = *(const h8v*)&Af[0][3 * wm + i][quad][l16][0];
            a_l[i] = *(const h8v*)&Af[1][3 * wm + i][quad][l16][0];
            a_d[i] = a_l[i] * (_Float16)INV_SPLIT_SCALE;
        }
#pragma unroll
        for (int j = 0; j < 4; ++j) {
            h8v b_h = *(const h8v*)&Bf[0][4 * wn + j][quad][l16][0];
            h8v b_l = *(const h8v*)&Bf[1][4 * wn + j][quad][l16][0];
#pragma unroll
            for (int i = 0; i < 3; ++i) {
                acc0[i][j] = __builtin_amdgcn_mfma_f32_16x16x32_f16(a_h[i], b_h, acc0[i][j], 0, 0, 0);
                acc1[i][j] = __builtin_amdgcn_mfma_f32_16x16x32_f16(a_h[i], b_l, acc1[i][j], 0, 0, 0);
                acc1[i][j] = __builtin_amdgcn_mfma_f32_16x16x32_f16(a_l[i], b_h, acc1[i][j], 0, 0, 0);
                acc1[i][j] = __builtin_amdgcn_mfma_f32_16x16x32_f16(a_d[i], b_l, acc1[i][j], 0, 0, 0);
            }
        }
    }
    // epilogue: C/D layout col=lane&15, row=quad*4+reg. Contiguous 16-lane atomics.
#pragma unroll
    for (int i = 0; i < 3; ++i) {
        int r0 = 48 * wm + 16 * i + quad * 4;
#pragma unroll
        for (int j = 0; j < 4; ++j) {
            int gc = 64 * wn + 16 * j + l16;
#pragma unroll
            for (int reg = 0; reg < 4; ++reg) {
                float v = fmaf(acc1[i][j][reg], INV_SPLIT_SCALE, acc0[i][j][reg]);
                if (RELU) v = fmaxf(v, 0.f);
                atomicAdd(O + (size_t)(r0 + reg) * 128 + gc, v);
            }
        }
    }
}

// ---------------- zero helper ----------------
__global__ void k_zero(float* __restrict__ p, int n4) {
    int i = blockIdx.x * blockDim.x + threadIdx.x;
    if (i < n4) ((float4*)p)[i] = float4{0.f, 0.f, 0.f, 0.f};
}

// ---------------- kernel 4: fused head ----------------
__global__ __launch_bounds__(256) void k_head(const float* __restrict__ h3,
        const float* __restrict__ st_w1, const float* __restrict__ st_b1,
        const float* __restrict__ st_w2, const float* __restrict__ st_b2,
        const float* __restrict__ rescale_w, float* __restrict__ out) {
    __shared__ float hL[64][132];
    __shared__ float w1L[64][132];
    __shared__ float ytL[64][68];
    __shared__ float w2L[32][68];
    __shared__ float b1L[64], b2L[32];
    int t = threadIdx.x;
    int r0 = blockIdx.x * 64;
#pragma unroll
    for (int p = 0; p < 8; ++p) {   // h rows 64x128 = 2048 f4
        int idx = t + p * 256;
        int r = idx >> 5, q = idx & 31;
        *(float4*)&hL[r][q * 4] = *(const float4*)(h3 + (size_t)(r0 + r) * 128 + q * 4);
    }
#pragma unroll
    for (int p = 0; p < 8; ++p) {   // w1 64x128
        int idx = t + p * 256;
        int r = idx >> 5, q = idx & 31;
        *(float4*)&w1L[r][q * 4] = *(const float4*)(st_w1 + (size_t)r * 128 + q * 4);
    }
#pragma unroll
    for (int p = 0; p < 2; ++p) {   // w2 32x64 = 512 f4
        int idx = t + p * 256;
        int r = idx >> 4, q = idx & 15;
        *(float4*)&w2L[r][q * 4] = *(const float4*)(st_w2 + (size_t)r * 64 + q * 4);
    }
    if (t < 64) b1L[t] = st_b1[t];
    else if (t < 96) b2L[t - 64] = st_b2[t - 64];
    __syncthreads();
    // phase 1: y = h @ w1^T + b1, tanh
    int tx = t & 15, ty = t >> 4;
    float acc[4][4] = {};
    for (int d = 0; d < 128; ++d) {
        float a[4], w[4];
#pragma unroll
        for (int i = 0; i < 4; ++i) a[i] = hL[ty + 16 * i][d];
#pragma unroll
        for (int j = 0; j < 4; ++j) w[j] = w1L[tx + 16 * j][d];
#pragma unroll
        for (int i = 0; i < 4; ++i)
#pragma unroll
            for (int j = 0; j < 4; ++j)
                acc[i][j] = fmaf(a[i], w[j], acc[i][j]);
    }
#pragma unroll
    for (int i = 0; i < 4; ++i)
#pragma unroll
        for (int j = 0; j < 4; ++j)
            ytL[ty + 16 * i][tx + 16 * j] = tanhf(acc[i][j] + b1L[tx + 16 * j]);
    __syncthreads();
    // phase 2: z = yt @ w2^T + b2; split into s (tanh*exp(rescale)) and t
    int tx8 = t & 7, ty32 = t >> 3;
    float acc2[2][4] = {};
    for (int d = 0; d < 64; ++d) {
        float a[2], w[4];
#pragma unroll
        for (int i = 0; i < 2; ++i) a[i] = ytL[ty32 + 32 * i][d];
#pragma unroll
        for (int j = 0; j < 4; ++j) w[j] = w2L[tx8 + 8 * j][d];
#pragma unroll
        for (int i = 0; i < 2; ++i)
#pragma unroll
            for (int j = 0; j < 4; ++j)
                acc2[i][j] = fmaf(a[i], w[j], acc2[i][j]);
    }
    float er = expf(rescale_w[0]);
#pragma unroll
    for (int i = 0; i < 2; ++i) {
        int r = r0 + ty32 + 32 * i;
#pragma unroll
        for (int j = 0; j < 4; ++j) {
            int c = tx8 + 8 * j;
            float z = acc2[i][j] + b2L[c];
            if (c < 16) out[(size_t)r * 16 + c] = er * tanhf(z);
            else        out[(size_t)(ROWS + r) * 16 + (c - 16)] = z;
        }
    }
}

extern "C" void kernel_launch(void* const* d_in, const int* in_sizes, int n_in,
                              void* d_out, int out_size, void* d_ws, size_t ws_size,
                              hipStream_t stream) {
    const float* x     = (const float*)d_in[0];
    const float* adj   = (const float*)d_in[1];
    const float* emb_w = (const float*)d_in[2];
    const float* gc1   = (const float*)d_in[3];
    const float* gc2   = (const float*)d_in[4];
    const float* gc3   = (const float*)d_in[5];
    const float* st_w1 = (const float*)d_in[6];
    const float* st_b1 = (const float*)d_in[7];
    const float* st_w2 = (const float*)d_in[8];
    const float* st_b2 = (const float*)d_in[9];
    const float* resc  = (const float*)d_in[10];
    float* out = (float*)d_out;
    float* ws  = (float*)d_ws;

    // workspace layout: M1 24KB | hA 12.6MB | hB 12.6MB | Sh 18.9MB | Sl 18.9MB ≈ 63 MB
    float* M1 = ws;                            // 6144 f
    float* hA = M1 + 6144;                     // 3145728 f (h1, later h3)
    float* hB = hA + 3145728;                  // 3145728 f (h2)
    _Float16* Sh = (_Float16*)(hB + 3145728);  // 9437184 halves
    _Float16* Sl = Sh + 9437184;               // 9437184 halves

    // layer 1 (non-reassociated): M1 = emb^T@W1; S1 = x@M1; h1 = sum_e relu(adj@S1)
    k_prep<<<1, 256, 0, stream>>>(emb_w, gc1, M1);
    k_support16<<<dim3(384, 3), 256, 0, stream>>>(x, M1, Sh, Sl);
    k_zero<<<3072, 256, 0, stream>>>(hA, 786432);
    k_adj_mfma<1><<<dim3(4, 3, 64), 256, 0, stream>>>(adj, Sh, Sl, hA);
    // layer 2
    k_support<<<dim3(384, 3), 256, 0, stream>>>(hA, gc2, Sh, Sl);
    k_zero<<<3072, 256, 0, stream>>>(hB, 786432);
    k_adj_mfma<1><<<dim3(4, 3, 64), 256, 0, stream>>>(adj, Sh, Sl, hB);
    // layer 3 (no relu)
    k_support<<<dim3(384, 3), 256, 0, stream>>>(hB, gc3, Sh, Sl);
    k_zero<<<3072, 256, 0, stream>>>(hA, 786432);
    k_adj_mfma<0><<<dim3(4, 3, 64), 256, 0, stream>>>(adj, Sh, Sl, hA);
    // head
    k_head<<<384, 256, 0, stream>>>(hA, st_w1, st_b1, st_w2, st_b2, resc, out);
}